// Round 1
// baseline (2100.376 us; speedup 1.0000x reference)
//
#include <hip/hip_runtime.h>
#include <cstddef>
#include <cstdint>

// LSTM_27934467293427 — R5: kill the per-step vmcnt(0) barrier drain in k2.
// __syncthreads() forces s_waitcnt vmcnt(0) before s_barrier, draining the
// per-step gx global prefetch on the serial chain (~1200 cy/step exposed
// latency). Replace with raw s_barrier + lgkmcnt(0)-only wait: LDS (h
// double-buffer) ordering is preserved, global loads stay in flight.
// K1 unchanged: gx = X·Wih^T + bias via split-bf16 MFMA.

namespace {

constexpr int B_ = 256, S_ = 2048, E_ = 128, H_ = 64, G_ = 256, H2_ = 2;

typedef short short8 __attribute__((ext_vector_type(8)));
typedef float f4 __attribute__((ext_vector_type(4)));

__device__ __forceinline__ float sigm(float x) {
    return __builtin_amdgcn_rcpf(1.0f + __expf(-x));
}
__device__ __forceinline__ float tanh_fast(float x) {
    return 1.0f - 2.0f * __builtin_amdgcn_rcpf(1.0f + __expf(2.0f * x));
}
__device__ __forceinline__ float dot4(float4 a, float4 b) {
    return a.x * b.x + a.y * b.y + a.z * b.z + a.w * b.w;
}
__device__ __forceinline__ short f2bf(float f) {  // RNE float->bf16
    union { float f; uint32_t u; } a; a.f = f;
    uint32_t r = a.u + 0x7FFFu + ((a.u >> 16) & 1u);
    return (short)(r >> 16);
}
__device__ __forceinline__ float bf2f(short s) {
    union { uint32_t u; float f; } a; a.u = ((uint32_t)(uint16_t)s) << 16;
    return a.f;
}
__device__ __forceinline__ void cvt8(float4 a, float4 b, short8& hi, short8& lo) {
    float v[8] = {a.x, a.y, a.z, a.w, b.x, b.y, b.z, b.w};
    #pragma unroll
    for (int i = 0; i < 8; ++i) {
        short h = f2bf(v[i]);
        hi[i] = h;
        lo[i] = f2bf(v[i] - bf2f(h));
    }
}
#define PIN4(v) asm volatile("" : "+v"(v.x), "+v"(v.y), "+v"(v.z), "+v"(v.w))

// Workgroup barrier that only drains LDS traffic. Unlike __syncthreads(),
// this does NOT wait vmcnt(0), so global prefetch loads (gx pipeline) and
// one-shot global stores stay in flight across steps. lgkmcnt(0) from every
// wave covers both RAW (h write -> read) and WAR (h read -> next-step
// overwrite) hazards on the LDS double buffer. "memory" clobbers pin LDS
// ops on their side of the barrier; volatile asm cannot cross the
// side-effecting s_barrier builtin.
__device__ __forceinline__ void sync_lds_only() {
    asm volatile("s_waitcnt lgkmcnt(0)" ::: "memory");
    __builtin_amdgcn_s_barrier();
    asm volatile("" ::: "memory");
}

// ---------------- K1: gx[b][tau][j] = sum_e x[b,cs+tau,e]*Wih[j,e] + bias[j] ----
// grid (B*Tc/128, 2), 256 thr. Wave w owns 32 cols; block owns 128 rows (8 slabs).
// MFMA 16x16x32 bf16, split precision: Ah*Bh + Al*Bh + Ah*Bl.
__global__ __launch_bounds__(256) void k1_gemm(
    const float* __restrict__ x, const int* __restrict__ lengths,
    const float* __restrict__ Wih, const float* __restrict__ bih,
    const float* __restrict__ bhh, float* __restrict__ gx, int cs, int tcLog)
{
    const int Tc = 1 << tcLog;
    const int t = threadIdx.x;
    const int lane = t & 63, wv = t >> 6;
    const int lm = lane & 15, quad = lane >> 4;
    const int nbase = blockIdx.y * 128 + wv * 32;
    const int rowblk = blockIdx.x * 128;

    // B-fragments (weights), held in registers for all 8 slabs.
    short8 Bh[2][4], Bl[2][4];
    float bias[2];
    #pragma unroll
    for (int nt = 0; nt < 2; ++nt) {
        const int n = nbase + nt * 16 + lm;
        bias[nt] = bih[n] + bhh[n];
        #pragma unroll
        for (int kk = 0; kk < 4; ++kk) {
            const float4* wp = (const float4*)(Wih + n * E_ + kk * 32 + quad * 8);
            cvt8(wp[0], wp[1], Bh[nt][kk], Bl[nt][kk]);
        }
    }

    for (int slab = 0; slab < 8; ++slab) {
        const int row0 = rowblk + slab * 16;
        const int b = row0 >> tcLog;
        const int tb = row0 & (Tc - 1);
        int len = lengths[b]; len = len < 1 ? 1 : (len > S_ ? S_ : len);
        if (cs + tb >= len) continue;

        // A-fragments: row m = lm, k = quad*8 + j (+32*kk)
        const float* xr = x + ((size_t)b * S_ + cs + tb + lm) * E_;
        short8 Ah[4], Al[4];
        #pragma unroll
        for (int kk = 0; kk < 4; ++kk) {
            const float4* ap = (const float4*)(xr + kk * 32 + quad * 8);
            cvt8(ap[0], ap[1], Ah[kk], Al[kk]);
        }
        f4 acc[2] = {{0,0,0,0},{0,0,0,0}};
        #pragma unroll
        for (int kk = 0; kk < 4; ++kk) {
            #pragma unroll
            for (int nt = 0; nt < 2; ++nt) {
                acc[nt] = __builtin_amdgcn_mfma_f32_16x16x32_bf16(Ah[kk], Bh[nt][kk], acc[nt], 0, 0, 0);
                acc[nt] = __builtin_amdgcn_mfma_f32_16x16x32_bf16(Al[kk], Bh[nt][kk], acc[nt], 0, 0, 0);
                acc[nt] = __builtin_amdgcn_mfma_f32_16x16x32_bf16(Ah[kk], Bl[nt][kk], acc[nt], 0, 0, 0);
            }
        }
        // D: col = lane&15, row = quad*4 + r (m89/m91-verified)
        float* gp = gx + ((size_t)b * Tc + tb) * G_;
        #pragma unroll
        for (int nt = 0; nt < 2; ++nt) {
            #pragma unroll
            for (int r = 0; r < 4; ++r) {
                gp[(quad * 4 + r) * G_ + nbase + nt * 16 + lm] = acc[nt][r] + bias[nt];
            }
        }
    }
}

// ---------------- K2: recurrence over one chunk [cs, cs+Tc) ---------------------
// 320 thr: t<256 gates (p=t>>2, q=t&3, gate j=q*64+p), wave 4 = head.
__global__ __launch_bounds__(320, 1) void k2_recur(
    const float* __restrict__ gx, const int* __restrict__ lengths,
    const float* __restrict__ Whh, const float* __restrict__ hWih,
    const float* __restrict__ hWhh, const float* __restrict__ hbih,
    const float* __restrict__ hbhh, float* __restrict__ out,
    float* __restrict__ stH, float* __restrict__ stC, float* __restrict__ stHK,
    int cs, int Tc)
{
    const int b = blockIdx.x, t = threadIdx.x;
    int len = lengths[b]; len = len < 1 ? 1 : (len > S_ ? S_ : len);
    if (cs > len) return;
    const int ce = cs + Tc;

    __shared__ __align__(16) float h_lds[2][H_];

    const bool isGate = t < 256;
    const int p = (t >> 2) & 63, q = t & 3;

    // Rotated gate weights: P_k accumulates gate (q^k) -> shuffle-transpose reduce.
    float4 wh[4][4];
    if (isGate) {
        #pragma unroll
        for (int k = 0; k < 4; ++k) {
            const int g = q ^ k;
            const float4* wp = (const float4*)(Whh + (g * 64 + p) * H_ + q * 16);
            #pragma unroll
            for (int i = 0; i < 4; ++i) wh[k][i] = wp[i];
        }
        #pragma unroll
        for (int k = 0; k < 4; ++k) {
            #pragma unroll
            for (int i = 0; i < 4; ++i) PIN4(wh[k][i]);
        }
    }

    // Head wave: th<52, ko=th>>1 (k=ko>>1, o=ko&1), half=th&1 covers 32 h-elems.
    const int th = t - 256;
    const bool isHead = (t >= 256) && (th < 52);
    const int ko = (th >> 1) & 31, half = th & 1;
    const int hk_k = ko >> 1, hk_o = ko & 1;
    float4 wk[8] = {};
    float hb = 0.f, w0 = 0.f, w1 = 0.f;
    if (isHead) {
        const int r = hk_k * 2 + hk_o;
        const float4* kp = (const float4*)(hWih + r * H_ + half * 32);
        #pragma unroll
        for (int i = 0; i < 8; ++i) wk[i] = kp[i];
        hb = hbih[r] + hbhh[r];
        w0 = hWhh[r * 2 + 0];
        w1 = hWhh[r * 2 + 1];
        #pragma unroll
        for (int i = 0; i < 8; ++i) PIN4(wk[i]);
    }

    float c = 0.f, hk = 0.f;
    if (cs == 0) {
        if (t < 64) h_lds[0][t] = 0.f;
    } else {
        if (t < 64) h_lds[cs & 1][t] = stH[b * 64 + t];
        if (isGate && q == 0) c = stC[b * 64 + p];
        if (isHead && half == 0) hk = stHK[b * 32 + ko];
    }
    __syncthreads();

    // gx prefetch pipeline (distance 2), thread t reads gx[.][q*64+p]
    const float* gxp = gx + (size_t)b * Tc * G_ + (q * 64 + p);
    float gxa = 0.f, gxb = 0.f;
    if (isGate) {
        if (cs < len) gxa = gxp[0];
        if (cs + 1 < len && cs + 1 < ce) gxb = gxp[G_];
    }

    auto headStep = [&](int u, const float* hbuf) {
        // computes hk_{u-1} from h_{u-1}; writes output when u == len
        const float4* hv = (const float4*)(hbuf + half * 32);
        float ph = 0.f;
        #pragma unroll
        for (int i = 0; i < 8; ++i) ph += dot4(wk[i], hv[i]);
        ph += __shfl_xor(ph, 1);
        const float partner = __shfl_xor(hk, 2);
        if (half == 0) {
            const float h0 = (hk_o == 0) ? hk : partner;
            const float h1 = (hk_o == 0) ? partner : hk;
            hk = tanh_fast(ph + hb + w0 * h0 + w1 * h1);
            if (u == len) out[(hk_k * B_ + b) * H2_ + hk_o] = sigm(hk);
        }
    };

    for (int u = cs; u < ce; ++u) {
        const float* hbuf = h_lds[u & 1];       // h_{u-1}
        if (u >= 1 && isHead) headStep(u, hbuf);
        if (u == len) return;                    // uniform: all threads exit

        if (isGate) {
            const float4* hv = (const float4*)(hbuf + q * 16);
            const float4 h0 = hv[0], h1 = hv[1], h2 = hv[2], h3 = hv[3];
            float P0 = dot4(wh[0][0], h0) + dot4(wh[0][1], h1) + dot4(wh[0][2], h2) + dot4(wh[0][3], h3);
            float P1 = dot4(wh[1][0], h0) + dot4(wh[1][1], h1) + dot4(wh[1][2], h2) + dot4(wh[1][3], h3);
            float P2 = dot4(wh[2][0], h0) + dot4(wh[2][1], h1) + dot4(wh[2][2], h2) + dot4(wh[2][3], h3);
            float P3 = dot4(wh[3][0], h0) + dot4(wh[3][1], h1) + dot4(wh[3][2], h2) + dot4(wh[3][3], h3);
            // transpose-reduce: lane q ends with full dot of gate q
            float a_  = P0 + __shfl_xor(P1, 1);
            float b2_ = P2 + __shfl_xor(P3, 1);
            float v   = a_ + __shfl_xor(b2_, 2) + gxa;
            // activation: q==2 -> tanh(v) = 2*sigm(2v)-1, else sigm(v)
            const bool isg = (q == 2);
            const float s = sigm(isg ? 2.f * v : v);
            const float act = isg ? 2.f * s - 1.f : s;
            const float r1 = __shfl_xor(act, 1);
            const float r2 = __shfl_xor(act, 2);
            const float r3 = __shfl_xor(act, 3);
            if (q == 0) {
                c = r1 * c + act * r2;                  // c = f*c + i*g
                h_lds[(u + 1) & 1][p] = r3 * tanh_fast(c);
            }
            gxa = gxb;
            const int un = u + 2;
            gxb = (un < len && un < ce) ? gxp[(size_t)(un - cs) * G_] : 0.f;
        }
        sync_lds_only();   // LDS-only barrier: gx prefetch stays in flight
    }

    // chunk fully processed (len >= ce): persist state
    if (t < 64) stH[b * 64 + t] = h_lds[ce & 1][t];
    if (isGate && q == 0) stC[b * 64 + p] = c;
    if (isHead && half == 0) stHK[b * 32 + ko] = hk;

    if (ce == S_ && len == S_) {
        // lagged final head for h_{S-1}
        if (isHead) headStep(S_, h_lds[S_ & 1]);
    }
}

}  // namespace

extern "C" void kernel_launch(void* const* d_in, const int* in_sizes, int n_in,
                              void* d_out, int out_size, void* d_ws, size_t ws_size,
                              hipStream_t stream) {
    const float* x    = (const float*)d_in[0];
    const int*   len  = (const int*)d_in[1];
    const float* Wih  = (const float*)d_in[2];
    const float* Whh  = (const float*)d_in[3];
    const float* bih  = (const float*)d_in[4];
    const float* bhh  = (const float*)d_in[5];
    const float* hWih = (const float*)d_in[6];
    const float* hWhh = (const float*)d_in[7];
    const float* hbih = (const float*)d_in[8];
    const float* hbhh = (const float*)d_in[9];
    float* out = (float*)d_out;

    // pick chunk length fitting the workspace (gx chunk + 160KB state)
    int tcLog = 8;  // Tc = 256
    while (tcLog > 5) {
        size_t need = (size_t)B_ * ((size_t)1 << tcLog) * G_ * 4 + 160 * 1024;
        if (need <= ws_size) break;
        --tcLog;
    }
    const int Tc = 1 << tcLog;
    float* gxbuf = (float*)d_ws;
    size_t gxBytes = (size_t)B_ * Tc * G_ * 4;
    float* stH  = (float*)((char*)d_ws + gxBytes);
    float* stC  = stH + B_ * 64;
    float* stHK = stC + B_ * 64;

    for (int cs = 0; cs < S_; cs += Tc) {
        dim3 g1(B_ * Tc / 128, 2);
        hipLaunchKernelGGL(k1_gemm, g1, dim3(256), 0, stream,
                           x, len, Wih, bih, bhh, gxbuf, cs, tcLog);
        hipLaunchKernelGGL(k2_recur, dim3(B_), dim3(320), 0, stream,
                           gxbuf, len, Whh, hWih, hWhh, hbih, hbhh, out,
                           stH, stC, stHK, cs, Tc);
    }
}